// Round 1
// baseline (556.032 us; speedup 1.0000x reference)
//
#include <hip/hip_runtime.h>

typedef __attribute__((ext_vector_type(8))) short short8;
typedef __attribute__((ext_vector_type(4))) float f32x4;

#define DEV static __device__ __forceinline__

DEV unsigned short f2bf(float f) {
  union { float f; unsigned u; } c;
  c.f = f;
  unsigned r = (c.u + 0x7fffu + ((c.u >> 16) & 1u)) >> 16;
  return (unsigned short)r;
}

DEV short8 pack2(float4 a, float4 b) {
  short8 r;
  r[0] = (short)f2bf(a.x); r[1] = (short)f2bf(a.y);
  r[2] = (short)f2bf(a.z); r[3] = (short)f2bf(a.w);
  r[4] = (short)f2bf(b.x); r[5] = (short)f2bf(b.y);
  r[6] = (short)f2bf(b.z); r[7] = (short)f2bf(b.w);
  return r;
}

constexpr int CDIM = 1024, TT = 2048, NH = 16, DK = 64, BHD = 64;
constexpr int BM = 128, BN = 128, BK = 64;

// ---------------- QKV projection: C[m][o] = sum_c X[m][c]*W[o][c] + b[o] ----
// scatter into per-head Q/K/V bf16 buffers [B*H][T][64]; Q pre-scaled 0.125
__global__ void qkv_gemm(const float* __restrict__ X, const float* __restrict__ W,
                         const float* __restrict__ bias,
                         unsigned short* __restrict__ Qb, unsigned short* __restrict__ Kb,
                         unsigned short* __restrict__ Vb) {
  __shared__ unsigned short As[BM][BK + 8];
  __shared__ unsigned short Bs[BN][BK + 8];
  const int tid = threadIdx.x;
  const int lane = tid & 63, wv = tid >> 6;
  const int wr = wv >> 1, wc = wv & 1;
  const int lo = lane & 15, lg = lane >> 4;
  const int m0 = blockIdx.x * BM, n0 = blockIdx.y * BN;

  f32x4 acc[4][4];
  const f32x4 fz = {0.f, 0.f, 0.f, 0.f};
#pragma unroll
  for (int i = 0; i < 4; ++i)
#pragma unroll
    for (int j = 0; j < 4; ++j) acc[i][j] = fz;

  const int srow = tid >> 1, sc0 = (tid & 1) * 32;
  const float* aptr = X + (size_t)(m0 + srow) * CDIM + sc0;
  const float* bptr = W + (size_t)(n0 + srow) * CDIM + sc0;

  for (int k0 = 0; k0 < CDIM; k0 += BK) {
#pragma unroll
    for (int i = 0; i < 4; ++i) {
      float4 a0 = *(const float4*)(aptr + k0 + i * 8);
      float4 a1 = *(const float4*)(aptr + k0 + i * 8 + 4);
      *(short8*)&As[srow][sc0 + i * 8] = pack2(a0, a1);
      float4 b0 = *(const float4*)(bptr + k0 + i * 8);
      float4 b1 = *(const float4*)(bptr + k0 + i * 8 + 4);
      *(short8*)&Bs[srow][sc0 + i * 8] = pack2(b0, b1);
    }
    __syncthreads();
#pragma unroll
    for (int kk = 0; kk < BK / 32; ++kk) {
      short8 af[4], bfr[4];
#pragma unroll
      for (int mi = 0; mi < 4; ++mi)
        af[mi] = *(const short8*)&As[wr * 64 + mi * 16 + lo][kk * 32 + lg * 8];
#pragma unroll
      for (int ni = 0; ni < 4; ++ni)
        bfr[ni] = *(const short8*)&Bs[wc * 64 + ni * 16 + lo][kk * 32 + lg * 8];
#pragma unroll
      for (int mi = 0; mi < 4; ++mi)
#pragma unroll
        for (int ni = 0; ni < 4; ++ni)
          acc[mi][ni] = __builtin_amdgcn_mfma_f32_16x16x32_bf16(af[mi], bfr[ni], acc[mi][ni], 0, 0, 0);
    }
    __syncthreads();
  }

#pragma unroll
  for (int ni = 0; ni < 4; ++ni) {
    const int o = n0 + wc * 64 + ni * 16 + lo;
    const float bv = bias[o];
    const int h = o / 192;
    const int rem = o - h * 192;
    const int which = rem >> 6;
    const int d = rem & 63;
    unsigned short* base = which == 0 ? Qb : (which == 1 ? Kb : Vb);
    const float qs = which == 0 ? 0.125f : 1.0f;
#pragma unroll
    for (int mi = 0; mi < 4; ++mi) {
#pragma unroll
      for (int r = 0; r < 4; ++r) {
        const int m = m0 + wr * 64 + mi * 16 + lg * 4 + r;
        const int b = m >> 11, t = m & 2047;
        const float v = (acc[mi][ni][r] + bv) * qs;
        base[(((size_t)(b * NH + h)) * TT + t) * DK + d] = f2bf(v);
      }
    }
  }
}

// ---------------- Flash attention, causal, QBLK=64 (4 waves x 16 rows) ------
__global__ void attn_fwd(const unsigned short* __restrict__ Qb,
                         const unsigned short* __restrict__ Kb,
                         const unsigned short* __restrict__ Vb,
                         unsigned short* __restrict__ Ctx) {
  __shared__ unsigned short Ks[64][72];
  __shared__ unsigned short Vt[64][72];
  __shared__ unsigned short Ps[4][16][72];
  const int tid = threadIdx.x;
  const int lane = tid & 63, wv = tid >> 6;
  const int lo = lane & 15, lg = lane >> 4;
  const int qt = (int)gridDim.x - 1 - (int)blockIdx.x;  // long blocks first
  const int bh = blockIdx.y;
  const int q0 = qt * 64;
  const unsigned short* Qp = Qb + (size_t)bh * TT * DK;
  const unsigned short* Kp = Kb + (size_t)bh * TT * DK;
  const unsigned short* Vp = Vb + (size_t)bh * TT * DK;

  short8 qf[2];
  {
    const int qrow = q0 + wv * 16 + lo;
    qf[0] = *(const short8*)&Qp[(size_t)qrow * DK + lg * 8];
    qf[1] = *(const short8*)&Qp[(size_t)qrow * DK + 32 + lg * 8];
  }

  f32x4 oacc[4];
  const f32x4 fz = {0.f, 0.f, 0.f, 0.f};
#pragma unroll
  for (int i = 0; i < 4; ++i) oacc[i] = fz;
  float m_r[4], l_r[4];
#pragma unroll
  for (int r = 0; r < 4; ++r) { m_r[r] = -1e30f; l_r[r] = 0.f; }

  const int strow = tid >> 2, stc0 = (tid & 3) * 16;

  for (int kvt = 0; kvt <= qt; ++kvt) {
    const int kv0 = kvt * 64;
    {
      const unsigned short* ks = &Kp[(size_t)(kv0 + strow) * DK + stc0];
      *(short8*)&Ks[strow][stc0] = *(const short8*)ks;
      *(short8*)&Ks[strow][stc0 + 8] = *(const short8*)(ks + 8);
      const unsigned short* vs = &Vp[(size_t)(kv0 + strow) * DK + stc0];
      short8 v0 = *(const short8*)vs;
      short8 v1 = *(const short8*)(vs + 8);
#pragma unroll
      for (int i = 0; i < 8; ++i) Vt[stc0 + i][strow] = (unsigned short)v0[i];
#pragma unroll
      for (int i = 0; i < 8; ++i) Vt[stc0 + 8 + i][strow] = (unsigned short)v1[i];
    }
    __syncthreads();

    f32x4 s[4];
#pragma unroll
    for (int nf = 0; nf < 4; ++nf) {
      s[nf] = fz;
#pragma unroll
      for (int kk = 0; kk < 2; ++kk) {
        const short8 kf = *(const short8*)&Ks[nf * 16 + lo][kk * 32 + lg * 8];
        s[nf] = __builtin_amdgcn_mfma_f32_16x16x32_bf16(qf[kk], kf, s[nf], 0, 0, 0);
      }
    }

    const bool diag = (kvt == qt);
    float p[4][4];
    float pm[4] = {-1e30f, -1e30f, -1e30f, -1e30f};
#pragma unroll
    for (int nf = 0; nf < 4; ++nf)
#pragma unroll
      for (int r = 0; r < 4; ++r) {
        float sv = s[nf][r];
        if (diag) {
          const int ig = wv * 16 + lg * 4 + r;
          const int jg = nf * 16 + lo;
          if (jg > ig) sv = -1e30f;
        }
        p[nf][r] = sv;
        pm[r] = fmaxf(pm[r], sv);
      }
#pragma unroll
    for (int r = 0; r < 4; ++r) {
      float v = pm[r];
      v = fmaxf(v, __shfl_xor(v, 1));
      v = fmaxf(v, __shfl_xor(v, 2));
      v = fmaxf(v, __shfl_xor(v, 4));
      v = fmaxf(v, __shfl_xor(v, 8));
      pm[r] = v;
    }
    float sc_[4];
#pragma unroll
    for (int r = 0; r < 4; ++r) {
      const float mn = fmaxf(m_r[r], pm[r]);
      sc_[r] = expf(m_r[r] - mn);
      m_r[r] = mn;
    }
    float rs[4] = {0.f, 0.f, 0.f, 0.f};
#pragma unroll
    for (int nf = 0; nf < 4; ++nf)
#pragma unroll
      for (int r = 0; r < 4; ++r) {
        const float e = expf(p[nf][r] - m_r[r]);
        p[nf][r] = e;
        rs[r] += e;
      }
#pragma unroll
    for (int r = 0; r < 4; ++r) {
      float v = rs[r];
      v += __shfl_xor(v, 1);
      v += __shfl_xor(v, 2);
      v += __shfl_xor(v, 4);
      v += __shfl_xor(v, 8);
      l_r[r] = l_r[r] * sc_[r] + v;
    }
#pragma unroll
    for (int df = 0; df < 4; ++df)
#pragma unroll
      for (int r = 0; r < 4; ++r) oacc[df][r] *= sc_[r];
#pragma unroll
    for (int nf = 0; nf < 4; ++nf)
#pragma unroll
      for (int r = 0; r < 4; ++r)
        Ps[wv][lg * 4 + r][nf * 16 + lo] = f2bf(p[nf][r]);

    // PV: A = P (per-wave LDS), B = V^T (contiguous j reads)
#pragma unroll
    for (int kk = 0; kk < 2; ++kk) {
      const short8 pa = *(const short8*)&Ps[wv][lo][kk * 32 + lg * 8];
#pragma unroll
      for (int df = 0; df < 4; ++df) {
        const short8 vb = *(const short8*)&Vt[df * 16 + lo][kk * 32 + lg * 8];
        oacc[df] = __builtin_amdgcn_mfma_f32_16x16x32_bf16(pa, vb, oacc[df], 0, 0, 0);
      }
    }
    __syncthreads();
  }

  const int b = bh >> 4, h = bh & 15;
#pragma unroll
  for (int r = 0; r < 4; ++r) {
    const float inv = 1.0f / l_r[r];
    const int trow = q0 + wv * 16 + lg * 4 + r;
#pragma unroll
    for (int df = 0; df < 4; ++df) {
      const size_t idx = ((size_t)(b * TT + trow)) * CDIM + h * DK + df * 16 + lo;
      Ctx[idx] = f2bf(oacc[df][r] * inv);
    }
  }
}

// ---------------- Output projection: Out[m][o] = sum_c Ctx[m][c]*Wout[o][c]+b
__global__ void out_gemm(const unsigned short* __restrict__ A,
                         const float* __restrict__ W,
                         const float* __restrict__ bias,
                         float* __restrict__ Out) {
  __shared__ unsigned short As[BM][BK + 8];
  __shared__ unsigned short Bs[BN][BK + 8];
  const int tid = threadIdx.x;
  const int lane = tid & 63, wv = tid >> 6;
  const int wr = wv >> 1, wc = wv & 1;
  const int lo = lane & 15, lg = lane >> 4;
  const int m0 = blockIdx.x * BM, n0 = blockIdx.y * BN;

  f32x4 acc[4][4];
  const f32x4 fz = {0.f, 0.f, 0.f, 0.f};
#pragma unroll
  for (int i = 0; i < 4; ++i)
#pragma unroll
    for (int j = 0; j < 4; ++j) acc[i][j] = fz;

  const int srow = tid >> 1, sc0 = (tid & 1) * 32;
  const unsigned short* aptr = A + (size_t)(m0 + srow) * CDIM + sc0;
  const float* bptr = W + (size_t)(n0 + srow) * CDIM + sc0;

  for (int k0 = 0; k0 < CDIM; k0 += BK) {
#pragma unroll
    for (int i = 0; i < 4; ++i) {
      *(short8*)&As[srow][sc0 + i * 8] = *(const short8*)(aptr + k0 + i * 8);
      float4 b0 = *(const float4*)(bptr + k0 + i * 8);
      float4 b1 = *(const float4*)(bptr + k0 + i * 8 + 4);
      *(short8*)&Bs[srow][sc0 + i * 8] = pack2(b0, b1);
    }
    __syncthreads();
#pragma unroll
    for (int kk = 0; kk < BK / 32; ++kk) {
      short8 af[4], bfr[4];
#pragma unroll
      for (int mi = 0; mi < 4; ++mi)
        af[mi] = *(const short8*)&As[wr * 64 + mi * 16 + lo][kk * 32 + lg * 8];
#pragma unroll
      for (int ni = 0; ni < 4; ++ni)
        bfr[ni] = *(const short8*)&Bs[wc * 64 + ni * 16 + lo][kk * 32 + lg * 8];
#pragma unroll
      for (int mi = 0; mi < 4; ++mi)
#pragma unroll
        for (int ni = 0; ni < 4; ++ni)
          acc[mi][ni] = __builtin_amdgcn_mfma_f32_16x16x32_bf16(af[mi], bfr[ni], acc[mi][ni], 0, 0, 0);
    }
    __syncthreads();
  }

#pragma unroll
  for (int ni = 0; ni < 4; ++ni) {
    const int o = n0 + wc * 64 + ni * 16 + lo;
    const float bv = bias[o];
#pragma unroll
    for (int mi = 0; mi < 4; ++mi) {
#pragma unroll
      for (int r = 0; r < 4; ++r) {
        const int m = m0 + wr * 64 + mi * 16 + lg * 4 + r;
        Out[(size_t)m * CDIM + o] = acc[mi][ni][r] + bv;
      }
    }
  }
}

extern "C" void kernel_launch(void* const* d_in, const int* in_sizes, int n_in,
                              void* d_out, int out_size, void* d_ws, size_t ws_size,
                              hipStream_t stream) {
  const float* X = (const float*)d_in[0];
  const float* Wqkv = (const float*)d_in[1];
  const float* bqkv = (const float*)d_in[2];
  const float* Wout = (const float*)d_in[3];
  const float* bout = (const float*)d_in[4];
  float* Out = (float*)d_out;

  unsigned short* Qb = (unsigned short*)d_ws;
  unsigned short* Kb = Qb + (size_t)BHD * TT * DK;
  unsigned short* Vb = Kb + (size_t)BHD * TT * DK;
  unsigned short* Ctx = Vb + (size_t)BHD * TT * DK;

  qkv_gemm<<<dim3(64, 24), 256, 0, stream>>>(X, Wqkv, bqkv, Qb, Kb, Vb);
  attn_fwd<<<dim3(32, 64), 256, 0, stream>>>(Qb, Kb, Vb, Ctx);
  out_gemm<<<dim3(64, 8), 256, 0, stream>>>(Ctx, Wout, bout, Out);
}

// Round 2
// 278.552 us; speedup vs baseline: 1.9961x; 1.9961x over previous
//
#include <hip/hip_runtime.h>

typedef __attribute__((ext_vector_type(8))) short short8;
typedef __attribute__((ext_vector_type(4))) float f32x4;
typedef __attribute__((ext_vector_type(4))) unsigned int u32x4;
typedef __attribute__((ext_vector_type(4))) unsigned short u16x4;
typedef unsigned int u32;
typedef unsigned short u16;

#define DEV static __device__ __forceinline__

DEV u16 f2bf(float f) {
  union { float f; u32 u; } c; c.f = f;
  u32 r = (c.u + 0x7fffu + ((c.u >> 16) & 1u)) >> 16;
  return (u16)r;
}
DEV u32 packbf(float a, float b) {  // bf16 pair (round-half-away): lo=a, hi=b
  union { float f; u32 u; } x, y; x.f = a; y.f = b;
  return ((x.u + 0x8000u) >> 16) | ((y.u + 0x8000u) & 0xffff0000u);
}
DEV short8 pack8(float4 a, float4 b) {
  short8 r;
  r[0]=(short)f2bf(a.x); r[1]=(short)f2bf(a.y); r[2]=(short)f2bf(a.z); r[3]=(short)f2bf(a.w);
  r[4]=(short)f2bf(b.x); r[5]=(short)f2bf(b.y); r[6]=(short)f2bf(b.z); r[7]=(short)f2bf(b.w);
  return r;
}

DEV void glds16(const void* g, void* l) {
  __builtin_amdgcn_global_load_lds((const __attribute__((address_space(1))) u32*)g,
                                   (__attribute__((address_space(3))) u32*)l, 16, 0, 0);
}

constexpr int CDIM = 1024, TT = 2048, NH = 16, DK = 64;

// ---------------- fp32 -> bf16 conversion for X, W_qkv, W_out --------------
__global__ void conv_bf16(const float* __restrict__ X, const float* __restrict__ W1,
                          const float* __restrict__ W2, u16* __restrict__ Xb,
                          u16* __restrict__ W1b, u16* __restrict__ W2b) {
  const long n0 = 1048576, n1 = 393216, n2 = 131072;  // 8-elem groups
  for (long i = (long)blockIdx.x * blockDim.x + threadIdx.x; i < n0 + n1 + n2;
       i += (long)gridDim.x * blockDim.x) {
    const float* s; u16* d; long j = i;
    if (j < n0) { s = X; d = Xb; }
    else if (j < n0 + n1) { j -= n0; s = W1; d = W1b; }
    else { j -= n0 + n1; s = W2; d = W2b; }
    float4 a = ((const float4*)s)[2 * j];
    float4 b = ((const float4*)s)[2 * j + 1];
    ((short8*)d)[j] = pack8(a, b);
  }
}

// ---------------- QKV GEMM (m97 structure), scatter epilogue ----------------
// A = Xb [8192][1024], B = Wqkvb [3072][1024]; Q scaled 0.125; V stored transposed [bh][d][t]
__global__ void qkv_gemm2(const u16* __restrict__ A, const u16* __restrict__ B,
                          const float* __restrict__ bias, u16* __restrict__ Qb,
                          u16* __restrict__ Kb, u16* __restrict__ VTb) {
  __shared__ u16 As[128][64];
  __shared__ u16 Bs[128][64];
  const int tid = threadIdx.x, lane = tid & 63, wv = tid >> 6;
  const int wr = wv >> 1, wc = wv & 1, lo = lane & 15, lg = lane >> 4;
  const int m0 = blockIdx.x * 128, n0 = blockIdx.y * 128;
  const int rin = lane >> 3, blk = lane & 7;

  f32x4 acc[4][4];
  const f32x4 fz = {0.f, 0.f, 0.f, 0.f};
#pragma unroll
  for (int i = 0; i < 4; ++i)
#pragma unroll
    for (int j = 0; j < 4; ++j) acc[i][j] = fz;

  for (int k0 = 0; k0 < CDIM; k0 += 64) {
    const u16* ga = A + (size_t)(m0 + 32 * wv + rin) * CDIM + k0 + blk * 8;
    const u16* gb = B + (size_t)(n0 + 32 * wv + rin) * CDIM + k0 + blk * 8;
#pragma unroll
    for (int i = 0; i < 4; ++i) glds16(ga + (size_t)(8 * i) * CDIM, &As[32 * wv + 8 * i][0]);
#pragma unroll
    for (int i = 0; i < 4; ++i) glds16(gb + (size_t)(8 * i) * CDIM, &Bs[32 * wv + 8 * i][0]);
    __syncthreads();
#pragma unroll
    for (int kk = 0; kk < 2; ++kk) {
      short8 af[4], bf[4];
#pragma unroll
      for (int mi = 0; mi < 4; ++mi) af[mi] = *(const short8*)&As[wr * 64 + mi * 16 + lo][kk * 32 + lg * 8];
#pragma unroll
      for (int ni = 0; ni < 4; ++ni) bf[ni] = *(const short8*)&Bs[wc * 64 + ni * 16 + lo][kk * 32 + lg * 8];
#pragma unroll
      for (int mi = 0; mi < 4; ++mi)
#pragma unroll
        for (int ni = 0; ni < 4; ++ni)
          acc[mi][ni] = __builtin_amdgcn_mfma_f32_16x16x32_bf16(af[mi], bf[ni], acc[mi][ni], 0, 0, 0);
    }
    __syncthreads();
  }

#pragma unroll
  for (int ni = 0; ni < 4; ++ni) {
    const int o = n0 + wc * 64 + ni * 16 + lo;
    const float bv = bias[o];
    const int h = o / 192, rem = o - h * 192, which = rem >> 6, d = rem & 63;
#pragma unroll
    for (int mi = 0; mi < 4; ++mi) {
      const int mb = m0 + wr * 64 + mi * 16 + lg * 4;
      const int bb = mb >> 11, t0 = mb & 2047;
      const int bh = bb * NH + h;
      if (which == 2) {
        u16x4 pk;
#pragma unroll
        for (int r = 0; r < 4; ++r) pk[r] = f2bf(acc[mi][ni][r] + bv);
        *(u16x4*)&VTb[((size_t)bh * DK + d) * TT + t0] = pk;
      } else if (which == 1) {
#pragma unroll
        for (int r = 0; r < 4; ++r)
          Kb[((size_t)bh * TT + t0 + r) * DK + d] = f2bf(acc[mi][ni][r] + bv);
      } else {
#pragma unroll
        for (int r = 0; r < 4; ++r)
          Qb[((size_t)bh * TT + t0 + r) * DK + d] = f2bf((acc[mi][ni][r] + bv) * 0.125f);
      }
    }
  }
}

// ---------------- Flash attention: QBLK=128 (4 waves x 32 rows), KVBLK=64 ---
// swapped QK^T (mfma(K,Q)) -> in-lane softmax; P via swizzled per-wave LDS; V^T input.
__global__ void attn2(const u16* __restrict__ Qb, const u16* __restrict__ Kb,
                      const u16* __restrict__ VTb, u16* __restrict__ Ctx) {
  __shared__ u16 Kls[2][64][64];
  __shared__ u16 Vls[2][64][64];
  __shared__ u32 Ps[4][2][16][32];
  const int tid = threadIdx.x, lane = tid & 63, wv = tid >> 6;
  const int lo = lane & 15, lg = lane >> 4;
  const int qt = (int)gridDim.x - 1 - (int)blockIdx.x;  // long blocks first
  const int bh = blockIdx.y;
  const int q0w = qt * 128 + wv * 32;
  const u16* Qp = Qb + (size_t)bh * TT * DK;
  const u16* Kp = Kb + (size_t)bh * TT * DK;
  const u16* Vp = VTb + (size_t)bh * DK * TT;
  const int rin = lane >> 3, blk = lane & 7;

  short8 qw[2][2];
#pragma unroll
  for (int qf = 0; qf < 2; ++qf)
#pragma unroll
    for (int kk = 0; kk < 2; ++kk)
      qw[qf][kk] = *(const short8*)&Qp[(size_t)(q0w + qf * 16 + lo) * DK + kk * 32 + lg * 8];

  f32x4 oacc[2][4];
  const f32x4 fz = {0.f, 0.f, 0.f, 0.f};
#pragma unroll
  for (int qf = 0; qf < 2; ++qf)
#pragma unroll
    for (int df = 0; df < 4; ++df) oacc[qf][df] = fz;
  float m_s[2] = {-1e30f, -1e30f}, l_s[2] = {0.f, 0.f};

  const int nt = 2 * qt + 2;

#define STAGE(bufi, kvt_)                                                              \
  {                                                                                    \
    const int kv_ = (kvt_) * 64;                                                       \
    const int r0_ = wv * 16;                                                           \
    _Pragma("unroll") for (int i_ = 0; i_ < 2; ++i_) {                                 \
      glds16(&Kp[(size_t)(kv_ + r0_ + 8 * i_ + rin) * DK + ((blk ^ rin) * 8)],         \
             &Kls[bufi][r0_ + 8 * i_][0]);                                             \
    }                                                                                  \
    _Pragma("unroll") for (int i_ = 0; i_ < 2; ++i_) {                                 \
      glds16(&Vp[(size_t)(r0_ + 8 * i_ + rin) * TT + kv_ + ((blk ^ rin) * 8)],         \
             &Vls[bufi][r0_ + 8 * i_][0]);                                             \
    }                                                                                  \
  }

  STAGE(0, 0);
  __syncthreads();
  int buf = 0;
  for (int kvt = 0; kvt < nt; ++kvt) {
    const int kv0 = kvt * 64;
    if (kvt + 1 < nt) STAGE(buf ^ 1, kvt + 1);
    if (kv0 <= q0w + 31) {
      // ---- QK^T (swapped: A=K rows->s, B=Q cols->q) ----
      f32x4 sA[2][4];
#pragma unroll
      for (int qf = 0; qf < 2; ++qf)
#pragma unroll
        for (int nf = 0; nf < 4; ++nf) sA[qf][nf] = fz;
#pragma unroll
      for (int kk = 0; kk < 2; ++kk)
#pragma unroll
        for (int nf = 0; nf < 4; ++nf) {
          const short8 kf = *(const short8*)&Kls[buf][nf * 16 + lo][(kk * 32 + lg * 8) ^ ((lo & 7) << 3)];
          sA[0][nf] = __builtin_amdgcn_mfma_f32_16x16x32_bf16(kf, qw[0][kk], sA[0][nf], 0, 0, 0);
          sA[1][nf] = __builtin_amdgcn_mfma_f32_16x16x32_bf16(kf, qw[1][kk], sA[1][nf], 0, 0, 0);
        }
      // ---- online softmax, P pack into per-wave swizzled LDS ----
      float scq[2];
#pragma unroll
      for (int qf = 0; qf < 2; ++qf) {
        const int qrow = q0w + qf * 16 + lo;
        float pm = -1e30f;
#pragma unroll
        for (int nf = 0; nf < 4; ++nf)
#pragma unroll
          for (int r = 0; r < 4; ++r) {
            const int sg = kv0 + nf * 16 + lg * 4 + r;
            float v = sA[qf][nf][r];
            v = (sg <= qrow) ? v : -1e30f;
            sA[qf][nf][r] = v;
            pm = fmaxf(pm, v);
          }
        pm = fmaxf(pm, __shfl_xor(pm, 16));
        pm = fmaxf(pm, __shfl_xor(pm, 32));
        const float mn = fmaxf(m_s[qf], pm);
        const float sc = __expf(m_s[qf] - mn);
        m_s[qf] = mn; scq[qf] = sc;
        float rs = 0.f;
#pragma unroll
        for (int nf = 0; nf < 4; ++nf) {
          const float p0 = __expf(sA[qf][nf][0] - mn);
          const float p1 = __expf(sA[qf][nf][1] - mn);
          const float p2 = __expf(sA[qf][nf][2] - mn);
          const float p3 = __expf(sA[qf][nf][3] - mn);
          rs += (p0 + p1) + (p2 + p3);
          Ps[wv][qf][lo][(nf * 8 + lg * 2 + 0) ^ ((lo & 7) << 2)] = packbf(p0, p1);
          Ps[wv][qf][lo][(nf * 8 + lg * 2 + 1) ^ ((lo & 7) << 2)] = packbf(p2, p3);
        }
        rs += __shfl_xor(rs, 16);
        rs += __shfl_xor(rs, 32);
        l_s[qf] = l_s[qf] * sc + rs;
      }
      // ---- rescale O ----
#pragma unroll
      for (int qf = 0; qf < 2; ++qf) {
        const float s0 = scq[qf];
#pragma unroll
        for (int r = 0; r < 4; ++r) {
          const float sr = __shfl(s0, lg * 4 + r);
#pragma unroll
          for (int df = 0; df < 4; ++df) oacc[qf][df][r] *= sr;
        }
      }
      // ---- PV: A = P (from Ps), B = V^T ----
#pragma unroll
      for (int kk = 0; kk < 2; ++kk) {
        short8 pa[2];
#pragma unroll
        for (int qf = 0; qf < 2; ++qf) {
          union { u32x4 w; short8 s; } cv;
          cv.w = *(const u32x4*)&Ps[wv][qf][lo][(kk * 16 + lg * 4) ^ ((lo & 7) << 2)];
          pa[qf] = cv.s;
        }
#pragma unroll
        for (int df = 0; df < 4; ++df) {
          const short8 vb = *(const short8*)&Vls[buf][df * 16 + lo][(kk * 32 + lg * 8) ^ ((lo & 7) << 3)];
          oacc[0][df] = __builtin_amdgcn_mfma_f32_16x16x32_bf16(pa[0], vb, oacc[0][df], 0, 0, 0);
          oacc[1][df] = __builtin_amdgcn_mfma_f32_16x16x32_bf16(pa[1], vb, oacc[1][df], 0, 0, 0);
        }
      }
    }
    __syncthreads();
    buf ^= 1;
  }

  const int b = bh >> 4, h = bh & 15;
#pragma unroll
  for (int qf = 0; qf < 2; ++qf) {
    const float il = 1.0f / l_s[qf];
#pragma unroll
    for (int r = 0; r < 4; ++r) {
      const float ir = __shfl(il, lg * 4 + r);
      const int t = q0w + qf * 16 + lg * 4 + r;
#pragma unroll
      for (int df = 0; df < 4; ++df)
        Ctx[((size_t)(b * TT + t)) * CDIM + h * DK + df * 16 + lo] = f2bf(oacc[qf][df][r] * ir);
    }
  }
}

// ---------------- Output GEMM (m97 structure), fp32 out + bias --------------
__global__ void out_gemm2(const u16* __restrict__ A, const u16* __restrict__ B,
                          const float* __restrict__ bias, float* __restrict__ Out) {
  __shared__ u16 As[128][64];
  __shared__ u16 Bs[128][64];
  const int tid = threadIdx.x, lane = tid & 63, wv = tid >> 6;
  const int wr = wv >> 1, wc = wv & 1, lo = lane & 15, lg = lane >> 4;
  const int m0 = blockIdx.x * 128, n0 = blockIdx.y * 128;
  const int rin = lane >> 3, blk = lane & 7;

  f32x4 acc[4][4];
  const f32x4 fz = {0.f, 0.f, 0.f, 0.f};
#pragma unroll
  for (int i = 0; i < 4; ++i)
#pragma unroll
    for (int j = 0; j < 4; ++j) acc[i][j] = fz;

  for (int k0 = 0; k0 < CDIM; k0 += 64) {
    const u16* ga = A + (size_t)(m0 + 32 * wv + rin) * CDIM + k0 + blk * 8;
    const u16* gb = B + (size_t)(n0 + 32 * wv + rin) * CDIM + k0 + blk * 8;
#pragma unroll
    for (int i = 0; i < 4; ++i) glds16(ga + (size_t)(8 * i) * CDIM, &As[32 * wv + 8 * i][0]);
#pragma unroll
    for (int i = 0; i < 4; ++i) glds16(gb + (size_t)(8 * i) * CDIM, &Bs[32 * wv + 8 * i][0]);
    __syncthreads();
#pragma unroll
    for (int kk = 0; kk < 2; ++kk) {
      short8 af[4], bf[4];
#pragma unroll
      for (int mi = 0; mi < 4; ++mi) af[mi] = *(const short8*)&As[wr * 64 + mi * 16 + lo][kk * 32 + lg * 8];
#pragma unroll
      for (int ni = 0; ni < 4; ++ni) bf[ni] = *(const short8*)&Bs[wc * 64 + ni * 16 + lo][kk * 32 + lg * 8];
#pragma unroll
      for (int mi = 0; mi < 4; ++mi)
#pragma unroll
        for (int ni = 0; ni < 4; ++ni)
          acc[mi][ni] = __builtin_amdgcn_mfma_f32_16x16x32_bf16(af[mi], bf[ni], acc[mi][ni], 0, 0, 0);
    }
    __syncthreads();
  }

#pragma unroll
  for (int ni = 0; ni < 4; ++ni) {
    const int o = n0 + wc * 64 + ni * 16 + lo;
    const float bv = bias[o];
#pragma unroll
    for (int mi = 0; mi < 4; ++mi)
#pragma unroll
      for (int r = 0; r < 4; ++r)
        Out[(size_t)(m0 + wr * 64 + mi * 16 + lg * 4 + r) * CDIM + o] = acc[mi][ni][r] + bv;
  }
}

extern "C" void kernel_launch(void* const* d_in, const int* in_sizes, int n_in,
                              void* d_out, int out_size, void* d_ws, size_t ws_size,
                              hipStream_t stream) {
  const float* X = (const float*)d_in[0];
  const float* Wqkv = (const float*)d_in[1];
  const float* bqkv = (const float*)d_in[2];
  const float* Wout = (const float*)d_in[3];
  const float* bout = (const float*)d_in[4];
  float* Out = (float*)d_out;

  u16* Xb  = (u16*)d_ws;              // 8,388,608
  u16* W1b = Xb + 8388608;            // 3,145,728
  u16* W2b = W1b + 3145728;           // 1,048,576
  u16* Qb  = W2b + 1048576;           // 8,388,608
  u16* Kb  = Qb + 8388608;            // 8,388,608
  u16* VTb = Kb + 8388608;            // 8,388,608 (transposed: [bh][d][t])
  u16* Ctx = VTb + 8388608;           // 8,388,608

  conv_bf16<<<1024, 256, 0, stream>>>(X, Wqkv, Wout, Xb, W1b, W2b);
  qkv_gemm2<<<dim3(64, 24), 256, 0, stream>>>(Xb, W1b, bqkv, Qb, Kb, VTb);
  attn2<<<dim3(16, 64), 256, 0, stream>>>(Qb, Kb, VTb, Ctx);
  out_gemm2<<<dim3(64, 8), 256, 0, stream>>>(Ctx, W2b, bout, Out);
}

// Round 3
// 187.036 us; speedup vs baseline: 2.9729x; 1.4893x over previous
//
#include <hip/hip_runtime.h>

typedef __attribute__((ext_vector_type(8))) short short8;
typedef __attribute__((ext_vector_type(4))) float f32x4;
typedef __attribute__((ext_vector_type(16))) float f32x16;
typedef __attribute__((ext_vector_type(4))) unsigned int u32x4;
typedef __attribute__((ext_vector_type(4))) unsigned short u16x4;
typedef unsigned int u32;
typedef unsigned short u16;

#define DEV static __device__ __forceinline__

DEV u16 f2bf(float f) {
  union { float f; u32 u; } c; c.f = f;
  u32 r = (c.u + 0x7fffu + ((c.u >> 16) & 1u)) >> 16;
  return (u16)r;
}
DEV short8 pack8(float4 a, float4 b) {
  short8 r;
  r[0]=(short)f2bf(a.x); r[1]=(short)f2bf(a.y); r[2]=(short)f2bf(a.z); r[3]=(short)f2bf(a.w);
  r[4]=(short)f2bf(b.x); r[5]=(short)f2bf(b.y); r[6]=(short)f2bf(b.z); r[7]=(short)f2bf(b.w);
  return r;
}
DEV u32 cvtpk(float lo, float hi) {  // packed bf16 pair, RTNE
  u32 r;
  asm("v_cvt_pk_bf16_f32 %0, %1, %2" : "=v"(r) : "v"(lo), "v"(hi));
  return r;
}

DEV void glds16(const void* g, void* l) {
  __builtin_amdgcn_global_load_lds((const __attribute__((address_space(1))) u32*)g,
                                   (__attribute__((address_space(3))) u32*)l, 16, 0, 0);
}

DEV f32x16 mfma32(short8 a, short8 b, f32x16 c) {
  return __builtin_amdgcn_mfma_f32_32x32x16_bf16(a, b, c, 0, 0, 0);
}

constexpr int CDIM = 1024, TT = 2048, NH = 16, DK = 64;
// Q pre-scale: 1/sqrt(64) * log2(e)  (softmax runs in exp2 domain)
#define QSC 0.1803368801111601f

// ---------------- fp32 -> bf16 conversion for X, W_qkv, W_out --------------
__global__ void conv_bf16(const float* __restrict__ X, const float* __restrict__ W1,
                          const float* __restrict__ W2, u16* __restrict__ Xb,
                          u16* __restrict__ W1b, u16* __restrict__ W2b) {
  const long n0 = 1048576, n1 = 393216, n2 = 131072;  // 8-elem groups
  for (long i = (long)blockIdx.x * blockDim.x + threadIdx.x; i < n0 + n1 + n2;
       i += (long)gridDim.x * blockDim.x) {
    const float* s; u16* d; long j = i;
    if (j < n0) { s = X; d = Xb; }
    else if (j < n0 + n1) { j -= n0; s = W1; d = W1b; }
    else { j -= n0 + n1; s = W2; d = W2b; }
    float4 a = ((const float4*)s)[2 * j];
    float4 b = ((const float4*)s)[2 * j + 1];
    ((short8*)d)[j] = pack8(a, b);
  }
}

// ---------------- QKV GEMM (m97 structure), scatter epilogue ----------------
__global__ void qkv_gemm2(const u16* __restrict__ A, const u16* __restrict__ B,
                          const float* __restrict__ bias, u16* __restrict__ Qb,
                          u16* __restrict__ Kb, u16* __restrict__ VTb) {
  __shared__ u16 As[128][64];
  __shared__ u16 Bs[128][64];
  const int tid = threadIdx.x, lane = tid & 63, wv = tid >> 6;
  const int wr = wv >> 1, wc = wv & 1, lo = lane & 15, lg = lane >> 4;
  const int m0 = blockIdx.x * 128, n0 = blockIdx.y * 128;
  const int rin = lane >> 3, blk = lane & 7;

  f32x4 acc[4][4];
  const f32x4 fz = {0.f, 0.f, 0.f, 0.f};
#pragma unroll
  for (int i = 0; i < 4; ++i)
#pragma unroll
    for (int j = 0; j < 4; ++j) acc[i][j] = fz;

  for (int k0 = 0; k0 < CDIM; k0 += 64) {
    const u16* ga = A + (size_t)(m0 + 32 * wv + rin) * CDIM + k0 + blk * 8;
    const u16* gb = B + (size_t)(n0 + 32 * wv + rin) * CDIM + k0 + blk * 8;
#pragma unroll
    for (int i = 0; i < 4; ++i) glds16(ga + (size_t)(8 * i) * CDIM, &As[32 * wv + 8 * i][0]);
#pragma unroll
    for (int i = 0; i < 4; ++i) glds16(gb + (size_t)(8 * i) * CDIM, &Bs[32 * wv + 8 * i][0]);
    __syncthreads();
#pragma unroll
    for (int kk = 0; kk < 2; ++kk) {
      short8 af[4], bf[4];
#pragma unroll
      for (int mi = 0; mi < 4; ++mi) af[mi] = *(const short8*)&As[wr * 64 + mi * 16 + lo][kk * 32 + lg * 8];
#pragma unroll
      for (int ni = 0; ni < 4; ++ni) bf[ni] = *(const short8*)&Bs[wc * 64 + ni * 16 + lo][kk * 32 + lg * 8];
#pragma unroll
      for (int mi = 0; mi < 4; ++mi)
#pragma unroll
        for (int ni = 0; ni < 4; ++ni)
          acc[mi][ni] = __builtin_amdgcn_mfma_f32_16x16x32_bf16(af[mi], bf[ni], acc[mi][ni], 0, 0, 0);
    }
    __syncthreads();
  }

#pragma unroll
  for (int ni = 0; ni < 4; ++ni) {
    const int o = n0 + wc * 64 + ni * 16 + lo;
    const float bv = bias[o];
    const int h = o / 192, rem = o - h * 192, which = rem >> 6, d = rem & 63;
#pragma unroll
    for (int mi = 0; mi < 4; ++mi) {
      const int mb = m0 + wr * 64 + mi * 16 + lg * 4;
      const int bb = mb >> 11, t0 = mb & 2047;
      const int bh = bb * NH + h;
      if (which == 2) {
        u16x4 pk;
#pragma unroll
        for (int r = 0; r < 4; ++r) pk[r] = f2bf(acc[mi][ni][r] + bv);
        *(u16x4*)&VTb[((size_t)bh * DK + d) * TT + t0] = pk;
      } else if (which == 1) {
#pragma unroll
        for (int r = 0; r < 4; ++r)
          Kb[((size_t)bh * TT + t0 + r) * DK + d] = f2bf(acc[mi][ni][r] + bv);
      } else {
#pragma unroll
        for (int r = 0; r < 4; ++r)
          Qb[((size_t)bh * TT + t0 + r) * DK + d] = f2bf((acc[mi][ni][r] + bv) * QSC);
      }
    }
  }
}

// ---------------- Flash attention v3: 32x32 MFMA, swapped QK^T, folded pairs
// Block = 4 waves x 32 q-rows = 128-q tile; handles q-tiles (j, 15-j) -> uniform work.
// Lane owns one q-row (lq = lane&31, duplicated across halves h = lane>>5).
__global__ void attn3(const u16* __restrict__ Qb, const u16* __restrict__ Kb,
                      const u16* __restrict__ VTb, u16* __restrict__ Ctx) {
  __shared__ u16 Kls[2][64][64];
  __shared__ u16 Vls[2][64][64];
  __shared__ float smw[4][32];
  const int tid = threadIdx.x, lane = tid & 63, wv = tid >> 6;
  const int lq = lane & 31, h = lane >> 5;
  const int pj = blockIdx.x;  // 0..7 pair index
  const int bh = blockIdx.y;
  const int bb = bh >> 4, head = bh & 15;
  const u16* Qp = Qb + (size_t)bh * TT * DK;
  const u16* Kp = Kb + (size_t)bh * TT * DK;
  const u16* Vp = VTb + (size_t)bh * DK * TT;
  const int rin = lane >> 3, blk = lane & 7;

#define STAGE3(bufi, kvt_)                                                         \
  {                                                                                \
    const int kv_ = (kvt_) * 64;                                                   \
    const int r0_ = wv * 16;                                                       \
    glds16(&Kp[(size_t)(kv_ + r0_ + rin) * DK + (blk ^ rin) * 8],                  \
           &Kls[bufi][r0_][0]);                                                    \
    glds16(&Kp[(size_t)(kv_ + r0_ + 8 + rin) * DK + (blk ^ rin) * 8],              \
           &Kls[bufi][r0_ + 8][0]);                                                \
    glds16(&Vp[(size_t)(r0_ + rin) * TT + kv_ + (blk ^ rin) * 8],                  \
           &Vls[bufi][r0_][0]);                                                    \
    glds16(&Vp[(size_t)(r0_ + 8 + rin) * TT + kv_ + (blk ^ rin) * 8],              \
           &Vls[bufi][r0_ + 8][0]);                                                \
  }

  for (int pi = 0; pi < 2; ++pi) {
    const int qtile = pi ? (15 - pj) : pj;
    const int q0w = qtile * 128 + wv * 32;
    const int qrow = q0w + lq;

    short8 qw[4];
#pragma unroll
    for (int kk = 0; kk < 4; ++kk)
      qw[kk] = *(const short8*)&Qp[(size_t)qrow * DK + kk * 16 + h * 8];

    f32x16 oa0, oa1;
#pragma unroll
    for (int r = 0; r < 16; ++r) { oa0[r] = 0.f; oa1[r] = 0.f; }
    float m_s = -1e30f, l_s = 0.f;

    const int nt = 2 * qtile + 2;
    STAGE3(0, 0);
    __syncthreads();
    int buf = 0;
    for (int kvt = 0; kvt < nt; ++kvt) {
      const int kv0 = kvt * 64;
      if (kvt + 1 < nt) STAGE3(buf ^ 1, kvt + 1);
      if (kv0 <= q0w + 31) {
        // ---- QK^T (swapped): A = K subtile rows, B = Q cols ----
        f32x16 s0, s1;
#pragma unroll
        for (int r = 0; r < 16; ++r) { s0[r] = 0.f; s1[r] = 0.f; }
        __builtin_amdgcn_s_setprio(1);
#pragma unroll
        for (int kk = 0; kk < 4; ++kk) {
          const short8 kf0 = *(const short8*)&Kls[buf][lq][(((2 * kk + h) ^ (lq & 7)) * 8)];
          const short8 kf1 = *(const short8*)&Kls[buf][32 + lq][(((2 * kk + h) ^ (lq & 7)) * 8)];
          s0 = mfma32(kf0, qw[kk], s0);
          s1 = mfma32(kf1, qw[kk], s1);
        }
        __builtin_amdgcn_s_setprio(0);
        // ---- mask (diagonal tiles only) + row max ----
        const bool diag = (kv0 + 63 > q0w);
        if (diag) {
          const int lim = qrow - kv0 - 4 * h;
#pragma unroll
          for (int r = 0; r < 16; ++r) {
            const int kl = (r & 3) + 8 * (r >> 2);
            s0[r] = (kl <= lim) ? s0[r] : -1e30f;
            s1[r] = (kl + 32 <= lim) ? s1[r] : -1e30f;
          }
        }
        float pm = -1e30f;
#pragma unroll
        for (int r = 0; r < 16; ++r) { pm = fmaxf(pm, s0[r]); pm = fmaxf(pm, s1[r]); }
        pm = fmaxf(pm, __shfl_xor(pm, 32));
        // ---- defer-max rescale (rare) ----
        if (__any(pm > m_s + 8.0f)) {
          const float mn = fmaxf(m_s, pm);
          const float sc = exp2f(m_s - mn);
          m_s = mn;
          l_s *= sc;
          smw[wv][lq] = sc;  // both halves write same value
          f32x4 g2[4];
#pragma unroll
          for (int j = 0; j < 4; ++j) g2[j] = *(const f32x4*)&smw[wv][4 * h + 8 * j];
#pragma unroll
          for (int r = 0; r < 16; ++r) {
            const float s = g2[r >> 2][r & 3];
            oa0[r] *= s; oa1[r] *= s;
          }
        }
        // ---- P = exp2(S - m), row-sum ----
        float rs = 0.f;
#pragma unroll
        for (int r = 0; r < 16; ++r) {
          const float e0 = exp2f(s0[r] - m_s);
          const float e1 = exp2f(s1[r] - m_s);
          s0[r] = e0; s1[r] = e1;
          rs += e0 + e1;
        }
        rs += __shfl_xor(rs, 32);
        l_s += rs;
        // ---- PV per k-subtile: in-register bf16 A-fragments ----
#pragma unroll
        for (int s = 0; s < 2; ++s) {
          u32 C[8], X[8];
#pragma unroll
          for (int j = 0; j < 8; ++j)
            C[j] = s ? cvtpk(s1[2 * j], s1[2 * j + 1]) : cvtpk(s0[2 * j], s0[2 * j + 1]);
#pragma unroll
          for (int j = 0; j < 8; ++j) X[j] = __shfl_xor(C[j], 32);
#pragma unroll
          for (int b = 0; b < 2; ++b) {
            union { u32x4 w; short8 s8; } pa;
            const int o = 4 * b;
            pa.w[0] = h ? X[o + 2] : C[o + 0];
            pa.w[1] = h ? X[o + 3] : C[o + 1];
            pa.w[2] = h ? C[o + 2] : X[o + 0];
            pa.w[3] = h ? C[o + 3] : X[o + 1];
            const int ks = 2 * s + b;
            const short8 vb0 = *(const short8*)&Vls[buf][lq][(((2 * ks + h) ^ (lq & 7)) * 8)];
            const short8 vb1 = *(const short8*)&Vls[buf][32 + lq][(((2 * ks + h) ^ (lq & 7)) * 8)];
            __builtin_amdgcn_s_setprio(1);
            oa0 = mfma32(pa.s8, vb0, oa0);
            oa1 = mfma32(pa.s8, vb1, oa1);
            __builtin_amdgcn_s_setprio(0);
          }
        }
      }
      __syncthreads();
      buf ^= 1;
    }

    // ---- epilogue: normalize by l, store ----
    smw[wv][lq] = 1.0f / l_s;
    f32x4 gg[4];
#pragma unroll
    for (int j = 0; j < 4; ++j) gg[j] = *(const f32x4*)&smw[wv][4 * h + 8 * j];
#pragma unroll
    for (int r = 0; r < 16; ++r) {
      const float sc = gg[r >> 2][r & 3];
      const int t = q0w + (r & 3) + 8 * (r >> 2) + 4 * h;
      const size_t rowb = ((size_t)(bb * TT + t)) * CDIM + head * DK;
      Ctx[rowb + lq] = f2bf(oa0[r] * sc);
      Ctx[rowb + 32 + lq] = f2bf(oa1[r] * sc);
    }
    __syncthreads();
  }
#undef STAGE3
}

// ---------------- Output GEMM (m97 structure), fp32 out + bias --------------
__global__ void out_gemm2(const u16* __restrict__ A, const u16* __restrict__ B,
                          const float* __restrict__ bias, float* __restrict__ Out) {
  __shared__ u16 As[128][64];
  __shared__ u16 Bs[128][64];
  const int tid = threadIdx.x, lane = tid & 63, wv = tid >> 6;
  const int wr = wv >> 1, wc = wv & 1, lo = lane & 15, lg = lane >> 4;
  const int m0 = blockIdx.x * 128, n0 = blockIdx.y * 128;
  const int rin = lane >> 3, blk = lane & 7;

  f32x4 acc[4][4];
  const f32x4 fz = {0.f, 0.f, 0.f, 0.f};
#pragma unroll
  for (int i = 0; i < 4; ++i)
#pragma unroll
    for (int j = 0; j < 4; ++j) acc[i][j] = fz;

  for (int k0 = 0; k0 < CDIM; k0 += 64) {
    const u16* ga = A + (size_t)(m0 + 32 * wv + rin) * CDIM + k0 + blk * 8;
    const u16* gb = B + (size_t)(n0 + 32 * wv + rin) * CDIM + k0 + blk * 8;
#pragma unroll
    for (int i = 0; i < 4; ++i) glds16(ga + (size_t)(8 * i) * CDIM, &As[32 * wv + 8 * i][0]);
#pragma unroll
    for (int i = 0; i < 4; ++i) glds16(gb + (size_t)(8 * i) * CDIM, &Bs[32 * wv + 8 * i][0]);
    __syncthreads();
#pragma unroll
    for (int kk = 0; kk < 2; ++kk) {
      short8 af[4], bf[4];
#pragma unroll
      for (int mi = 0; mi < 4; ++mi) af[mi] = *(const short8*)&As[wr * 64 + mi * 16 + lo][kk * 32 + lg * 8];
#pragma unroll
      for (int ni = 0; ni < 4; ++ni) bf[ni] = *(const short8*)&Bs[wc * 64 + ni * 16 + lo][kk * 32 + lg * 8];
#pragma unroll
      for (int mi = 0; mi < 4; ++mi)
#pragma unroll
        for (int ni = 0; ni < 4; ++ni)
          acc[mi][ni] = __builtin_amdgcn_mfma_f32_16x16x32_bf16(af[mi], bf[ni], acc[mi][ni], 0, 0, 0);
    }
    __syncthreads();
  }

#pragma unroll
  for (int ni = 0; ni < 4; ++ni) {
    const int o = n0 + wc * 64 + ni * 16 + lo;
    const float bv = bias[o];
#pragma unroll
    for (int mi = 0; mi < 4; ++mi)
#pragma unroll
      for (int r = 0; r < 4; ++r)
        Out[(size_t)(m0 + wr * 64 + mi * 16 + lg * 4 + r) * CDIM + o] = acc[mi][ni][r] + bv;
  }
}

extern "C" void kernel_launch(void* const* d_in, const int* in_sizes, int n_in,
                              void* d_out, int out_size, void* d_ws, size_t ws_size,
                              hipStream_t stream) {
  const float* X = (const float*)d_in[0];
  const float* Wqkv = (const float*)d_in[1];
  const float* bqkv = (const float*)d_in[2];
  const float* Wout = (const float*)d_in[3];
  const float* bout = (const float*)d_in[4];
  float* Out = (float*)d_out;

  u16* Xb  = (u16*)d_ws;              // 8,388,608
  u16* W1b = Xb + 8388608;            // 3,145,728
  u16* W2b = W1b + 3145728;           // 1,048,576
  u16* Qb  = W2b + 1048576;           // 8,388,608 (pre-scaled by QSC)
  u16* Kb  = Qb + 8388608;            // 8,388,608
  u16* VTb = Kb + 8388608;            // 8,388,608 (transposed: [bh][d][t])
  u16* Ctx = VTb + 8388608;           // 8,388,608

  conv_bf16<<<1024, 256, 0, stream>>>(X, Wqkv, Wout, Xb, W1b, W2b);
  qkv_gemm2<<<dim3(64, 24), 256, 0, stream>>>(Xb, W1b, bqkv, Qb, Kb, VTb);
  attn3<<<dim3(8, 64), 256, 0, stream>>>(Qb, Kb, VTb, Ctx);
  out_gemm2<<<dim3(64, 8), 256, 0, stream>>>(Ctx, W2b, bout, Out);
}